// Round 8
// baseline (25377.240 us; speedup 1.0000x reference)
//
#include <hip/hip_runtime.h>
#include <math.h>

// LSTM_53171695124900: 2-layer LSTM, H=1024, I=64, O=2, T=4096.
// Round-18: SINGLE-BARRIER, WAVE-HALF-PARALLEL, IN-WAVE GATE COMBINE.
// From r17 (7560us, 3 barriers, serial A+B): remap lanes so wave w owns
// unit (w&3) with gates in lane&3 -> reduce is 4x shfl_xor + 3 shfl
// (no g1/g2 LDS buffers, no S2/S3). Waves 0-3 run layer-1, waves 4-7
// run layer-2 CONCURRENTLY; the only sync is one __syncthreads per
// phase (staging handoff; wave-uniform divergence). No LDS counters
// (r16's failure). Double-buffered staging: phase-p reads fenced from
// phase-p+2 writes by S1(p+1). Weight LDS re-laid-out [j*256+k]
// (conflict-free); staging rows stride-36 u32 (2-way, free).
//   L1 phase p: poll h1(p-1) tag p -> stage -> S1 -> 32 dot2 (W_hh1
//     regs) + x.Wih1 -> in-wave reduce+cell -> publish h1(p) tag p+1.
//     p=TSTEPS: stage-only.
//   L2 phase p: poll h2(p-2) tag p (p>=2; p<2 zeroed rows, p=0 skip) ->
//     stage -> S1 -> 64 dot2 (W_ih2.h1(p-1) + W_hh2.h2(p-2), LDS) ->
//     in-wave reduce+cell -> publish h2(p-1) HIST ROW p-1 tag p+1.
// Epilogue hist: row t holds h2(t), tag t+2. Fallback out deferred via
// redF partials (flush at p+1; tail flushed post-loop).

#define HID 1024
#define DIN 64
#define TSTEPS 4096
#define NWG 256
#define TPB 512

typedef unsigned long long u64;
typedef unsigned int u32;
typedef _Float16 f16x2 __attribute__((ext_vector_type(2)));
typedef __fp16   g16x2 __attribute__((ext_vector_type(2)));

// ws layout in u64 (8B tagged f32+tag entries, r10-compatible):
//   [0, 2048)                 : h1, 2 slots x 1024 (entry = unit)
//   [2048, 2048 + 4097*1024)  : h2; hist row t = h2(t) tag t+2,
//                               fallback rows (t & 1)
#define H2_OFF 2048
#define WS_NEED_U64 (2048ull + 4097ull * 1024ull)
#define WS_NEED_BYTES (WS_NEED_U64 * 8ull)
#define WS_ZERO_BYTES 32768   // h1 slots (16KB) + h2 rows 0..1 (16KB)

// dynamic LDS: 4096 uint4 f16 weights (64KB) + 2 x dbuf stride-36 stages
#define WLDS_U4 4096
#define HSTRIDE 36
#define HBUF (HSTRIDE * 16)                    // 576 u32 per buffer
#define H1S_OFF (WLDS_U4 * 16)                 // 65536 B
#define H2S_OFF (H1S_OFF + 2 * HBUF * 4)       // +4608 B
#define DYN_LDS_BYTES (H2S_OFF + 2 * HBUF * 4) // 74752 B

// staging addr for u32 slot s (slot s = h elems 2s,2s+1):
// chunk c=s>>5 at stride 36 (16B-aligned, banks spread 2-way)
#define SADDR(s) (HSTRIDE * ((s) >> 5) + ((s) & 31))

__device__ __forceinline__ float sigmoid_f(float v) {
    return 1.0f / (1.0f + __expf(-v));
}
__device__ __forceinline__ float tanh_f(float v) {
    return 2.0f / (1.0f + __expf(-2.0f * v)) - 1.0f;
}

// relaxed agent-scope 8B atomics: coherent at IC
__device__ __forceinline__ void st_pair(u64* p, float h, u32 tag) {
    u64 pk = ((u64)tag << 32) | (u64)__float_as_uint(h);
    __hip_atomic_store(p, pk, __ATOMIC_RELAXED, __HIP_MEMORY_SCOPE_AGENT);
}
__device__ __forceinline__ u64 ld_pair(const u64* p) {
    return __hip_atomic_load(p, __ATOMIC_RELAXED, __HIP_MEMORY_SCOPE_AGENT);
}
#define PTAG(v) ((u32)((v) >> 32))
#define PVAL(v) (__uint_as_float((u32)(v)))

union U32H2 { u32 u; f16x2 h; g16x2 g; };
__device__ __forceinline__ u32 pk2(float a, float b) {
    U32H2 t; t.g = __builtin_amdgcn_cvt_pkrtz(a, b); return t.u;
}

#if defined(__has_builtin)
#if __has_builtin(__builtin_amdgcn_fdot2)
#define HAS_FDOT2 1
#endif
#endif
__device__ __forceinline__ float dot2f(u32 a, u32 b, float c) {
    U32H2 x, y; x.u = a; y.u = b;
#ifdef HAS_FDOT2
    return __builtin_amdgcn_fdot2(x.h, y.h, c, false);
#else
    float r = fmaf((float)x.h.x, (float)y.h.x, c);
    return fmaf((float)x.h.y, (float)y.h.y, r);
#endif
}

__device__ __forceinline__ uint4 pack4(float4 a, float4 b) {
    return make_uint4(pk2(a.x, a.y), pk2(a.z, a.w),
                      pk2(b.x, b.y), pk2(b.z, b.w));
}

#define PIN8() asm volatile("" : "+v"(qw0.x), "+v"(qw0.y), "+v"(qw0.z), \
    "+v"(qw0.w), "+v"(qw1.x), "+v"(qw1.y), "+v"(qw1.z), "+v"(qw1.w),    \
    "+v"(qw2.x), "+v"(qw2.y), "+v"(qw2.z), "+v"(qw2.w),                 \
    "+v"(qw3.x), "+v"(qw3.y), "+v"(qw3.z), "+v"(qw3.w));                \
    asm volatile("" : "+v"(qw4.x), "+v"(qw4.y), "+v"(qw4.z),            \
    "+v"(qw4.w), "+v"(qw5.x), "+v"(qw5.y), "+v"(qw5.z), "+v"(qw5.w),    \
    "+v"(qw6.x), "+v"(qw6.y), "+v"(qw6.z), "+v"(qw6.w),                 \
    "+v"(qw7.x), "+v"(qw7.y), "+v"(qw7.z), "+v"(qw7.w))

#define L1STEP(j, QW) do {                                          \
    uint4 hv = *(const uint4*)(hbA + 4*(j));                        \
    a0 = dot2f(hv.x, QW.x, a0); a1 = dot2f(hv.y, QW.y, a1);         \
    a0 = dot2f(hv.z, QW.z, a0); a1 = dot2f(hv.w, QW.w, a1);         \
} while (0)

#define L2STEPA(j) do {                                             \
    uint4 hv = *(const uint4*)(hbA + 4*(j));                        \
    uint4 w2 = wlds[(j)*256 + k];                                   \
    e0 = dot2f(hv.x, w2.x, e0); e1 = dot2f(hv.y, w2.y, e1);         \
    e0 = dot2f(hv.z, w2.z, e0); e1 = dot2f(hv.w, w2.w, e1);         \
} while (0)

#define L2STEPB(j) do {                                             \
    uint4 gv = *(const uint4*)(hbB + 4*(j));                        \
    uint4 w3 = wlds[2048 + (j)*256 + k];                            \
    e0 = dot2f(gv.x, w3.x, e0); e1 = dot2f(gv.y, w3.y, e1);         \
    e0 = dot2f(gv.z, w3.z, e0); e1 = dot2f(gv.w, w3.w, e1);         \
} while (0)

__global__ void
__attribute__((amdgpu_flat_work_group_size(TPB, TPB), amdgpu_waves_per_eu(2, 2)))
lstm_persistent(
    const float* __restrict__ x,
    const float* __restrict__ Wih1, const float* __restrict__ Whh1,
    const float* __restrict__ bih1, const float* __restrict__ bhh1,
    const float* __restrict__ Wih2, const float* __restrict__ Whh2,
    const float* __restrict__ bih2, const float* __restrict__ bhh2,
    const float* __restrict__ Wout, const float* __restrict__ bout,
    float* __restrict__ out, u64* __restrict__ ws, int use_hist)
{
    const int wg   = blockIdx.x;          // 0..255
    const int tid  = threadIdx.x;         // 0..511
    const int wave = tid >> 6;            // 0..7
    const int lane = tid & 63;
    const int isL2 = wave >> 2;           // waves 0-3: layer1, 4-7: layer2
    const int u    = wave & 3;            // unit 0..3
    const int g    = lane & 3;            // gate 0..3 (i,f,g,o)
    const int c    = lane >> 2;           // k-chunk 0..15 (64 elems each)
    const int k    = tid & 255;           // index within half
    const int R    = g * HID + (wg << 2) + u;   // gate row in [0,4096)

    u64* h1t = ws;
    u64* h2t = ws + H2_OFF;

    extern __shared__ __align__(16) char smem[];
    uint4* wlds = (uint4*)smem;                  // 64KB f16 weights (L2)
    u32*   h1s  = (u32*)(smem + H1S_OFF);        // 2 x 576 u32
    u32*   h2s  = (u32*)(smem + H2S_OFF);        // 2 x 576 u32

    __shared__ float red0[8], red1[8];
    __shared__ float redF0[2][4], redF1[2][4];

    // ---- per-half setup ----
    uint4 qw0 = {0,0,0,0}, qw1 = {0,0,0,0}, qw2 = {0,0,0,0}, qw3 = {0,0,0,0};
    uint4 qw4 = {0,0,0,0}, qw5 = {0,0,0,0}, qw6 = {0,0,0,0}, qw7 = {0,0,0,0};
    float4 wx4 = make_float4(0.f, 0.f, 0.f, 0.f);
    float4 wo0 = make_float4(0.f, 0.f, 0.f, 0.f);
    float4 wo1 = make_float4(0.f, 0.f, 0.f, 0.f);
    float bsum = 0.f;
    float creg = 0.f;    // c1 (L1, g==0 lanes) or c2 (L2, g==0 lanes)

    if (!isL2) {
        const float4* p1 = (const float4*)(Whh1 + (size_t)R * HID + (c << 6));
        qw0 = pack4(p1[0],  p1[1]);
        qw1 = pack4(p1[2],  p1[3]);
        qw2 = pack4(p1[4],  p1[5]);
        qw3 = pack4(p1[6],  p1[7]);
        qw4 = pack4(p1[8],  p1[9]);
        qw5 = pack4(p1[10], p1[11]);
        qw6 = pack4(p1[12], p1[13]);
        qw7 = pack4(p1[14], p1[15]);
        wx4 = *(const float4*)(Wih1 + (size_t)R * DIN + (c << 2));
        bsum = bih1[R] + bhh1[R];
    } else {
        // stage W_ih2/W_hh2 into LDS, layout [j*256 + k] (conflict-free)
        const float4* q2 = (const float4*)(Wih2 + (size_t)R * HID + (c << 6));
        const float4* q3 = (const float4*)(Whh2 + (size_t)R * HID + (c << 6));
        #pragma unroll
        for (int j = 0; j < 8; ++j)
            wlds[j * 256 + k] = pack4(q2[2*j], q2[2*j+1]);
        #pragma unroll
        for (int j = 0; j < 8; ++j)
            wlds[2048 + j * 256 + k] = pack4(q3[2*j], q3[2*j+1]);
        bsum = bih2[R] + bhh2[R];
        if (!use_hist && wg == 0) {
            wo0 = *(const float4*)(Wout + (k << 2));
            wo1 = *(const float4*)(Wout + HID + (k << 2));
        }
    }
    PIN8();

    __syncthreads();   // wlds staged

    for (int p = 0; p <= TSTEPS; ++p) {
        const int buf = p & 1;

        if (!isL2) {
            // ---- L1 poll: h1 entries 4k..4k+3, slot buf, tag p ----
            const u64* hp = h1t + (size_t)buf * 1024 + (k << 2);
            const u32 want = (u32)p;
            u64 e0 = ld_pair(hp),     e1 = ld_pair(hp + 1);
            u64 e2 = ld_pair(hp + 2), e3 = ld_pair(hp + 3);
            int guard = 0;
            while ((PTAG(e0) != want) | (PTAG(e1) != want) |
                   (PTAG(e2) != want) | (PTAG(e3) != want)) {
                if (PTAG(e0) != want) e0 = ld_pair(hp);
                if (PTAG(e1) != want) e1 = ld_pair(hp + 1);
                if (PTAG(e2) != want) e2 = ld_pair(hp + 2);
                if (PTAG(e3) != want) e3 = ld_pair(hp + 3);
                if (++guard > (1 << 17)) break;  // hang insurance only
            }
            u32* hb = h1s + buf * HBUF;
            hb[SADDR(2*k)]     = pk2(PVAL(e0), PVAL(e1));
            hb[SADDR(2*k + 1)] = pk2(PVAL(e2), PVAL(e3));
        } else {
            // ---- L2 poll: h2(p-2) tag p (p>=2); p==1 zeroed row 1;
            //      p==0 skipped (values unused -> avoids tag-0 WAR race)
            float v0 = 0.f, v1 = 0.f, v2 = 0.f, v3 = 0.f;
            if (p >= 1) {
                const u32 want = (p >= 2) ? (u32)p : 0u;
                const int row2 = (p >= 2) ? (use_hist ? (p - 2) : (p & 1)) : 1;
                const u64* hp = h2t + (size_t)row2 * 1024 + (k << 2);
                u64 e0 = ld_pair(hp),     e1 = ld_pair(hp + 1);
                u64 e2 = ld_pair(hp + 2), e3 = ld_pair(hp + 3);
                int guard = 0;
                while ((PTAG(e0) != want) | (PTAG(e1) != want) |
                       (PTAG(e2) != want) | (PTAG(e3) != want)) {
                    if (PTAG(e0) != want) e0 = ld_pair(hp);
                    if (PTAG(e1) != want) e1 = ld_pair(hp + 1);
                    if (PTAG(e2) != want) e2 = ld_pair(hp + 2);
                    if (PTAG(e3) != want) e3 = ld_pair(hp + 3);
                    if (++guard > (1 << 17)) break;  // hang insurance only
                }
                v0 = PVAL(e0); v1 = PVAL(e1); v2 = PVAL(e2); v3 = PVAL(e3);
            }
            u32* hb = h2s + buf * HBUF;
            hb[SADDR(2*k)]     = pk2(v0, v1);
            hb[SADDR(2*k + 1)] = pk2(v2, v3);

            // fallback partials for out[p-2] (values are h2(p-2), f32)
            if (!use_hist && wg == 0 && p >= 2) {
                float q0 = wo0.x*v0 + wo0.y*v1 + wo0.z*v2 + wo0.w*v3;
                float q1 = wo1.x*v0 + wo1.y*v1 + wo1.z*v2 + wo1.w*v3;
                #pragma unroll
                for (int m = 1; m < 64; m <<= 1) {
                    q0 += __shfl_xor(q0, m);
                    q1 += __shfl_xor(q1, m);
                }
                if (lane == 0) { redF0[buf][u] = q0; redF1[buf][u] = q1; }
            }
        }

        __syncthreads();   // S1: staging ready (ONLY barrier per phase)

        if (!isL2) {
            if (p < TSTEPS) {
                const u32* hbA = h1s + buf * HBUF + HSTRIDE * c;
                float a0 = 0.f, a1 = 0.f;
                L1STEP(0, qw0); L1STEP(1, qw1); L1STEP(2, qw2); L1STEP(3, qw3);
                L1STEP(4, qw4); L1STEP(5, qw5); L1STEP(6, qw6); L1STEP(7, qw7);
                const float4 xv4 = *(const float4*)(x + (size_t)p * DIN + (c << 2));
                a0 = fmaf(wx4.x, xv4.x, a0); a1 = fmaf(wx4.y, xv4.y, a1);
                a0 = fmaf(wx4.z, xv4.z, a0); a1 = fmaf(wx4.w, xv4.w, a1);
                float acc = a0 + a1;
                acc += __shfl_xor(acc, 4);
                acc += __shfl_xor(acc, 8);
                acc += __shfl_xor(acc, 16);
                acc += __shfl_xor(acc, 32);
                float val = acc + bsum;
                val = (g == 2) ? tanh_f(val) : sigmoid_f(val);
                float t1v = __shfl_xor(val, 1);
                float t2v = __shfl_xor(val, 2);
                float t3v = __shfl_xor(t1v, 2);
                if (g == 0) {
                    // val=i, t1v=f, t2v=g, t3v=o
                    float cn = t1v * creg + val * t2v;
                    creg = cn;
                    float hh = t3v * tanh_f(cn);
                    if (c == 0)
                        st_pair(h1t + (size_t)((p + 1) & 1) * 1024 + (wg << 2) + u,
                                hh, (u32)(p + 1));
                }
            }
            PIN8();
        } else {
            // deferred fallback flush: out[p-3] from partials of phase p-1
            if (!use_hist && wg == 0 && k == 0 && p >= 3) {
                const int rb = (p - 1) & 1;
                float o0 = bout[0] + redF0[rb][0] + redF0[rb][1]
                                   + redF0[rb][2] + redF0[rb][3];
                float o1 = bout[1] + redF1[rb][0] + redF1[rb][1]
                                   + redF1[rb][2] + redF1[rb][3];
                out[2*(p-3)+0] = o0;
                out[2*(p-3)+1] = o1;
            }
            if (p >= 1) {
                const u32* hbA = h1s + buf * HBUF + HSTRIDE * c;
                const u32* hbB = h2s + buf * HBUF + HSTRIDE * c;
                float e0 = 0.f, e1 = 0.f;
                L2STEPA(0); L2STEPA(1); L2STEPA(2); L2STEPA(3);
                L2STEPA(4); L2STEPA(5); L2STEPA(6); L2STEPA(7);
                L2STEPB(0); L2STEPB(1); L2STEPB(2); L2STEPB(3);
                L2STEPB(4); L2STEPB(5); L2STEPB(6); L2STEPB(7);
                float acc = e0 + e1;
                acc += __shfl_xor(acc, 4);
                acc += __shfl_xor(acc, 8);
                acc += __shfl_xor(acc, 16);
                acc += __shfl_xor(acc, 32);
                float val = acc + bsum;
                val = (g == 2) ? tanh_f(val) : sigmoid_f(val);
                float t1v = __shfl_xor(val, 1);
                float t2v = __shfl_xor(val, 2);
                float t3v = __shfl_xor(t1v, 2);
                if (g == 0) {
                    float cn = t1v * creg + val * t2v;
                    creg = cn;
                    float hh = t3v * tanh_f(cn);
                    if (c == 0) {
                        const int wr = use_hist ? (p - 1) : ((p - 1) & 1);
                        st_pair(h2t + (size_t)wr * 1024 + (wg << 2) + u,
                                hh, (u32)(p + 1));
                    }
                }
            }
        }
        // next phase's S1 fences staging buffer reuse (dbuf parity)
    }

    __syncthreads();   // rejoin halves before epilogue

    // ---- epilogue ----
    if (use_hist) {
        // hist row t holds h2(t) with tag t+2
        const float2 wo0e = *(const float2*)(Wout + (tid << 1));
        const float2 wo1e = *(const float2*)(Wout + HID + (tid << 1));
        const float bo0 = bout[0], bo1 = bout[1];
        for (int i = 0; i < 16; ++i) {
            const int t = (wg << 4) + i;
            const u64* hp = h2t + (size_t)t * 1024 + (tid << 1);
            const u32 want = (u32)(t + 2);
            u64 va, vb; int guard = 0;
            for (;;) {
                va = ld_pair(hp); vb = ld_pair(hp + 1);
                if ((PTAG(va) == want) && (PTAG(vb) == want)) break;
                if (++guard > (1 << 15)) break;
            }
            float h0 = PVAL(va), h1v = PVAL(vb);
            float q0 = wo0e.x * h0 + wo0e.y * h1v;
            float q1 = wo1e.x * h0 + wo1e.y * h1v;
            #pragma unroll
            for (int m = 1; m < 64; m <<= 1) {
                q0 += __shfl_xor(q0, m);
                q1 += __shfl_xor(q1, m);
            }
            if (lane == 0) { red0[wave] = q0; red1[wave] = q1; }
            __syncthreads();
            if (tid == 0) {
                float o0 = bo0, o1 = bo1;
                #pragma unroll
                for (int w = 0; w < 8; ++w) { o0 += red0[w]; o1 += red1[w]; }
                out[2*t+0] = o0;
                out[2*t+1] = o1;
            }
            __syncthreads();
        }
    } else if (wg == 0) {
        // flush out[T-2] from the phase-TSTEPS partials (buf 0)
        if (tid == 256) {
            float o0 = bout[0] + redF0[0][0] + redF0[0][1]
                               + redF0[0][2] + redF0[0][3];
            float o1 = bout[1] + redF1[0][0] + redF1[0][1]
                               + redF1[0][2] + redF1[0][3];
            out[2*(TSTEPS-2)+0] = o0;
            out[2*(TSTEPS-2)+1] = o1;
        }
        // final out[T-1]: h2(T-1) published phase TSTEPS -> fallback row
        // (TSTEPS-1)&1 = 1, tag TSTEPS+1
        const float2 wo0e = *(const float2*)(Wout + (tid << 1));
        const float2 wo1e = *(const float2*)(Wout + HID + (tid << 1));
        const u64* hp = h2t + (size_t)((TSTEPS - 1) & 1) * 1024 + (tid << 1);
        const u32 want = (u32)(TSTEPS + 1);
        u64 va, vb; int guard = 0;
        for (;;) {
            va = ld_pair(hp); vb = ld_pair(hp + 1);
            if ((PTAG(va) == want) && (PTAG(vb) == want)) break;
            if (++guard > (1 << 15)) break;
        }
        float h0 = PVAL(va), h1v = PVAL(vb);
        float q0 = wo0e.x * h0 + wo0e.y * h1v;
        float q1 = wo1e.x * h0 + wo1e.y * h1v;
        #pragma unroll
        for (int m = 1; m < 64; m <<= 1) {
            q0 += __shfl_xor(q0, m);
            q1 += __shfl_xor(q1, m);
        }
        if (lane == 0) { red0[wave] = q0; red1[wave] = q1; }
        __syncthreads();
        if (tid == 0) {
            float o0 = bout[0], o1 = bout[1];
            #pragma unroll
            for (int w = 0; w < 8; ++w) { o0 += red0[w]; o1 += red1[w]; }
            out[2*(TSTEPS-1)+0] = o0;
            out[2*(TSTEPS-1)+1] = o1;
        }
    }
}

extern "C" void kernel_launch(void* const* d_in, const int* in_sizes, int n_in,
                              void* d_out, int out_size, void* d_ws, size_t ws_size,
                              hipStream_t stream)
{
    const float* x    = (const float*)d_in[0];
    const float* Wih1 = (const float*)d_in[1];
    const float* Whh1 = (const float*)d_in[2];
    const float* bih1 = (const float*)d_in[3];
    const float* bhh1 = (const float*)d_in[4];
    const float* Wih2 = (const float*)d_in[5];
    const float* Whh2 = (const float*)d_in[6];
    const float* bih2 = (const float*)d_in[7];
    const float* bhh2 = (const float*)d_in[8];
    const float* Wout = (const float*)d_in[9];
    const float* bout = (const float*)d_in[10];
    float* out = (float*)d_out;
    u64*   ws  = (u64*)d_ws;

    const int use_hist = (ws_size >= WS_NEED_BYTES) ? 1 : 0;

    // allow >64KB dynamic LDS (idempotent, not stream-ordered: capture-safe)
    (void)hipFuncSetAttribute((const void*)lstm_persistent,
                              hipFuncAttributeMaxDynamicSharedMemorySize,
                              DYN_LDS_BYTES);

    // zero h1 slots + h2 rows 0..1 (ws re-poisoned before every call;
    // poison never equals a wanted tag, so un-zeroed hist rows are safe)
    (void)hipMemsetAsync(d_ws, 0, WS_ZERO_BYTES, stream);

    hipLaunchKernelGGL(lstm_persistent, dim3(NWG), dim3(TPB), DYN_LDS_BYTES,
                       stream,
                       x, Wih1, Whh1, bih1, bhh1,
                       Wih2, Whh2, bih2, bhh2,
                       Wout, bout, out, ws, use_hist);
}

// Round 9
// 7522.376 us; speedup vs baseline: 3.3736x; 3.3736x over previous
//
#include <hip/hip_runtime.h>
#include <math.h>

// LSTM_53171695124900: 2-layer LSTM, H=1024, I=64, O=2, T=4096.
// Persistent kernel, 256 WGs x 512 threads.
// Round-19 = FINAL RESTORE of the session-best verified kernel
// (r10/r17 lineage; 7475-7581us, absmax 2.441e-4).
// Structural search closed (7 topologies measured):
//   r11 reorder+deep poll   9.9ms  (poll issue-rate into IC hotspot)
//   r12 f16-packed h1       7.7ms  (=baseline, -19% traffic: kept)
//   r13 lgkm-only barriers  8.4ms  (drains weren't the stall)
//   r16 split + LDS ctrs   14.3ms  (counter handshakes re-serialize)
//   r18 1-barrier split    25.4ms  (uncoalesced 4-wave publishes: 4x
//        WRITE; naked publish->poll edge; blocking polls under S1)
// Why this structure wins: coalesced single-wave publishes (h1 tid<4,
// h2 tid4..7 -> one IC transaction each), EARLY h1 publish hidden under
// B-dot+S3, h2 poll issued at phase start and verified mid-phase.
// Remaining limit is a latency floor, not a roofline: 4096 serial steps
// x (IC store->remote-visibility + 256-WG convergence), ~800cy VALU/step
// available to hide ~700-900cy of fabric latency.

#define HID 1024
#define DIN 64
#define TSTEPS 4096
#define NWG 256
#define TPB 512

typedef unsigned long long u64;
typedef unsigned int u32;
typedef _Float16 f16x2 __attribute__((ext_vector_type(2)));
typedef __fp16   g16x2 __attribute__((ext_vector_type(2)));

// ws layout in u64 (8B tagged pairs):
//   [0, 2048)                 : h1 pairs, 2 slots x 1024
//   [2048, 2048 + 4097*1024)  : h2 pairs; hist mode = row per phase,
//                               fallback mode = rows (phase & 1)
#define H2_OFF 2048
#define WS_NEED_U64 (2048ull + 4097ull * 1024ull)
#define WS_NEED_BYTES (WS_NEED_U64 * 8ull)
#define WS_ZERO_BYTES 32768   // h1 slots (16KB) + h2 rows 0..1 (16KB)

// dynamic LDS: 8*512 uint4 f16 weights (64KB) + 2 x 640-u32 h staging
#define WLDS_U4 (8 * 512)
#define H1S_OFF (WLDS_U4 * 16)            // bytes
#define H2S_OFF (H1S_OFF + 640 * 4)
#define DYN_LDS_BYTES (H2S_OFF + 640 * 4) // 70656 B

__device__ __forceinline__ float sigmoid_f(float v) {
    return 1.0f / (1.0f + __expf(-v));
}
__device__ __forceinline__ float tanh_f(float v) {
    return 2.0f / (1.0f + __expf(-2.0f * v)) - 1.0f;
}

// relaxed agent-scope 8B atomics: coherent at IC, no cache-maintenance insts
__device__ __forceinline__ void st_pair(u64* p, float h, u32 tag) {
    u64 pk = ((u64)tag << 32) | (u64)__float_as_uint(h);
    __hip_atomic_store(p, pk, __ATOMIC_RELAXED, __HIP_MEMORY_SCOPE_AGENT);
}
__device__ __forceinline__ u64 ld_pair(const u64* p) {
    return __hip_atomic_load(p, __ATOMIC_RELAXED, __HIP_MEMORY_SCOPE_AGENT);
}
#define PTAG(v) ((u32)((v) >> 32))
#define PVAL(v) (__uint_as_float((u32)(v)))

// same 4 bytes seen as u32 / __fp16x2 (cvt_pkrtz) / _Float16x2 (fdot2)
union U32H2 { u32 u; f16x2 h; g16x2 g; };

// pack two f32 -> half2 u32 (v_cvt_pkrtz_f16_f32, single inst)
__device__ __forceinline__ u32 pk2(float a, float b) {
    U32H2 t; t.g = __builtin_amdgcn_cvt_pkrtz(a, b); return t.u;
}

#if defined(__has_builtin)
#if __has_builtin(__builtin_amdgcn_fdot2)
#define HAS_FDOT2 1
#endif
#endif

// f32 += half2 . half2  (v_dot2_f32_f16 when available)
__device__ __forceinline__ float dot2f(u32 a, u32 b, float c) {
    U32H2 x, y; x.u = a; y.u = b;
#ifdef HAS_FDOT2
    return __builtin_amdgcn_fdot2(x.h, y.h, c, false);
#else
    float r = fmaf((float)x.h.x, (float)y.h.x, c);
    return fmaf((float)x.h.y, (float)y.h.y, r);
#endif
}

#define PIN_W1() asm volatile("" : "+v"(w1p0), "+v"(w1p1), "+v"(w1p2), \
    "+v"(w1p3), "+v"(w1p4), "+v"(w1p5), "+v"(w1p6), "+v"(w1p7), \
    "+v"(w1p8), "+v"(w1p9), "+v"(w1pA), "+v"(w1pB), \
    "+v"(w1pC), "+v"(w1pD), "+v"(w1pE), "+v"(w1pF))

// A-step j (j=0..3): 8 h1 elems; W1 (reg half2s) -> accA, W2 (LDS) -> accB
#define ASTEP(j, P0, P1, P2, P3) do {                               \
    uint4 hv = *(const uint4*)(h1s + hbase + 4*(j));                \
    uint4 w2 = wlds[(j)*512 + tid];                                 \
    a0 = dot2f(hv.x, P0, a0); a1 = dot2f(hv.y, P1, a1);             \
    a0 = dot2f(hv.z, P2, a0); a1 = dot2f(hv.w, P3, a1);             \
    e0 = dot2f(hv.x, w2.x, e0); e1 = dot2f(hv.y, w2.y, e1);         \
    e0 = dot2f(hv.z, w2.z, e0); e1 = dot2f(hv.w, w2.w, e1);         \
} while (0)

// B-step j (j=0..3): 8 h2 elems; W3 (LDS) -> accB
#define BSTEP(j) do {                                               \
    uint4 gv = *(const uint4*)(h2s + hbase + 4*(j));                \
    uint4 w3 = wlds[(4+(j))*512 + tid];                             \
    e0 = dot2f(gv.x, w3.x, e0); e1 = dot2f(gv.y, w3.y, e1);         \
    e0 = dot2f(gv.z, w3.z, e0); e1 = dot2f(gv.w, w3.w, e1);         \
} while (0)

__global__ void
__attribute__((amdgpu_flat_work_group_size(TPB, TPB), amdgpu_waves_per_eu(2, 2)))
lstm_persistent(
    const float* __restrict__ x,
    const float* __restrict__ Wih1, const float* __restrict__ Whh1,
    const float* __restrict__ bih1, const float* __restrict__ bhh1,
    const float* __restrict__ Wih2, const float* __restrict__ Whh2,
    const float* __restrict__ bih2, const float* __restrict__ bhh2,
    const float* __restrict__ Wout, const float* __restrict__ bout,
    float* __restrict__ out, u64* __restrict__ ws, int use_hist)
{
    const int wg   = blockIdx.x;          // 0..255
    const int tid  = threadIdx.x;         // 0..511
    const int wave = tid >> 6;            // 0..7
    const int lane = tid & 63;
    const int gate = tid >> 7;            // 0..3 (i,f,g,o)
    const int rsub = (tid >> 5) & 3;      // local unit 0..3
    const int c    = tid & 31;            // k-chunk 0..31
    const int row  = gate * HID + (wg << 2) + rsub;   // gate row in [0,4096)
    const int kbase = c << 5;

    u64* h1t = ws;
    u64* h2t = ws + H2_OFF;

    // ---- dynamic LDS carve ----
    extern __shared__ __align__(16) char smem[];
    uint4* wlds = (uint4*)smem;                  // 64KB f16 weights
    u32*   h1s  = (u32*)(smem + H1S_OFF);        // 640 u32 (stride-20 rows)
    u32*   h2s  = (u32*)(smem + H2S_OFF);        // 640 u32

    // ---- one-time: stage W_ih2/W_hh2 rows into LDS as packed f16 ----
    {
        const float4* q2 = (const float4*)(Wih2 + (size_t)row * HID + kbase);
        const float4* q3 = (const float4*)(Whh2 + (size_t)row * HID + kbase);
        #pragma unroll
        for (int j = 0; j < 4; ++j) {
            float4 qa = q2[2*j], qb = q2[2*j+1];
            wlds[j * 512 + tid] = make_uint4(pk2(qa.x, qa.y), pk2(qa.z, qa.w),
                                             pk2(qb.x, qb.y), pk2(qb.z, qb.w));
        }
        #pragma unroll
        for (int j = 0; j < 4; ++j) {
            float4 qa = q3[2*j], qb = q3[2*j+1];
            wlds[(4+j) * 512 + tid] = make_uint4(pk2(qa.x, qa.y), pk2(qa.z, qa.w),
                                                 pk2(qb.x, qb.y), pk2(qb.z, qb.w));
        }
    }

    // ---- W_hh1 row chunk: 16 packed-half2 u32 registers ----
    const float4* p1 = (const float4*)(Whh1 + (size_t)row * HID + kbase);
    float4 f0 = p1[0], f1 = p1[1], f2 = p1[2], f3 = p1[3];
    float4 f4 = p1[4], f5 = p1[5], f6 = p1[6], f7 = p1[7];
    u32 w1p0 = pk2(f0.x, f0.y), w1p1 = pk2(f0.z, f0.w);
    u32 w1p2 = pk2(f1.x, f1.y), w1p3 = pk2(f1.z, f1.w);
    u32 w1p4 = pk2(f2.x, f2.y), w1p5 = pk2(f2.z, f2.w);
    u32 w1p6 = pk2(f3.x, f3.y), w1p7 = pk2(f3.z, f3.w);
    u32 w1p8 = pk2(f4.x, f4.y), w1p9 = pk2(f4.z, f4.w);
    u32 w1pA = pk2(f5.x, f5.y), w1pB = pk2(f5.z, f5.w);
    u32 w1pC = pk2(f6.x, f6.y), w1pD = pk2(f6.z, f6.w);
    u32 w1pE = pk2(f7.x, f7.y), w1pF = pk2(f7.z, f7.w);
    PIN_W1();

    const float2 wx = *(const float2*)(Wih1 + (size_t)row * DIN + (c << 1));
    const float bsum1 = bih1[row] + bhh1[row];
    const float bsum2 = bih2[row] + bhh2[row];

    __shared__ float g1[4][4], g2[4][4];
    __shared__ float c1s[4], c2s[4];
    __shared__ float red0[8], red1[8];
    if (tid < 4) { c1s[tid] = 0.0f; c2s[tid] = 0.0f; }

    // h staging: chunk rows of 16 half2-u32 + 4 pad (stride 20 u32, 80B)
    const int sdst = 20 * (tid >> 4) + (tid & 15);
    const int hbase = 20 * c;

    __syncthreads();   // wlds staged, c-state zeroed

    for (int p = 0; p <= TSTEPS; ++p) {
        const u64* h1p = h1t + (size_t)(p & 1) * 1024 + (tid << 1);
        const int h2row_c = (p > 0) ? (use_hist ? (p - 1) : ((p - 1) & 1)) : 0;
        const u64* h2p = h2t + (size_t)h2row_c * 1024 + (tid << 1);
        const u32 want1 = (u32)p;
        const u32 want2 = (p >= 2) ? (u32)p : 0u;

        const int tx = (p < TSTEPS) ? p : 0;
        const float2 xv = *(const float2*)(x + (size_t)tx * DIN + (c << 1));

        // ---- blocking poll: h1(p-1), tag p (published mid-phase p-1) ----
        u64 v1a, v1b;
        {
            int guard = 0;
            for (;;) {
                v1a = ld_pair(h1p); v1b = ld_pair(h1p + 1);
                if ((PTAG(v1a) == want1) & (PTAG(v1b) == want1)) break;
                if (++guard > (1 << 17)) break;  // hang insurance only
            }
        }
        // early h2 read attempt (verified after the A-dot)
        u64 v2a = ld_pair(h2p), v2b = ld_pair(h2p + 1);

        PIN_W1();   // keepalive: W1 VGPR-resident every phase

        h1s[sdst] = pk2(PVAL(v1a), PVAL(v1b));
        __syncthreads();   // S1: h1s staged

        // ---- A-dot: accA = W_hh1.h1 (+x); accB partial = W_ih2.h1 ----
        float a0 = 0.f, a1 = 0.f, e0 = 0.f, e1 = 0.f;
        ASTEP(0, w1p0, w1p1, w1p2, w1p3);
        ASTEP(1, w1p4, w1p5, w1p6, w1p7);
        ASTEP(2, w1p8, w1p9, w1pA, w1pB);
        ASTEP(3, w1pC, w1pD, w1pE, w1pF);
        a0 = fmaf(wx.x, xv.x, a0);
        a1 = fmaf(wx.y, xv.y, a1);

        float accA = a0 + a1;
        accA += __shfl_xor(accA, 1);
        accA += __shfl_xor(accA, 2);
        accA += __shfl_xor(accA, 4);
        accA += __shfl_xor(accA, 8);
        accA += __shfl_xor(accA, 16);
        if (c == 0) {
            float vA = accA + bsum1;
            g1[gate][rsub] = (gate == 2) ? tanh_f(vA) : sigmoid_f(vA);
        }

        // ---- finish h2 poll (usually already satisfied) + stage ----
        {
            int guard = 0;
            while (!((PTAG(v2a) == want2) & (PTAG(v2b) == want2))) {
                v2a = ld_pair(h2p); v2b = ld_pair(h2p + 1);
                if (++guard > (1 << 17)) break;  // hang insurance only
            }
        }
        float sb0 = PVAL(v2a), sb1 = PVAL(v2b);
        h2s[sdst] = pk2(sb0, sb1);
        __syncthreads();   // S2: g1 + h2s ready

        // ---- EARLY h1 publication: before the heavy B-part ----
        if (p < TSTEPS && tid < 4) {
            float iv = g1[0][tid], fv = g1[1][tid];
            float gv = g1[2][tid], ov = g1[3][tid];
            float cn = fv * c1s[tid] + iv * gv;
            c1s[tid] = cn;
            st_pair(h1t + (size_t)((p + 1) & 1) * 1024 + (wg << 2) + tid,
                    ov * tanh_f(cn), (u32)(p + 1));
        }

        // ---- B-dot: accB += W_hh2.h2 ----
        BSTEP(0); BSTEP(1); BSTEP(2); BSTEP(3);

        float accB = e0 + e1;
        accB += __shfl_xor(accB, 1);
        accB += __shfl_xor(accB, 2);
        accB += __shfl_xor(accB, 4);
        accB += __shfl_xor(accB, 8);
        accB += __shfl_xor(accB, 16);
        if (c == 0) {
            float vB = accB + bsum2;
            g2[gate][rsub] = (gate == 2) ? tanh_f(vB) : sigmoid_f(vB);
        }
        __syncthreads();   // S3: g2 ready; also fences LDS reuse next phase

        if (p >= 1 && tid >= 4 && tid < 8) {
            int u = tid - 4;
            float iv = g2[0][u], fv = g2[1][u];
            float gv = g2[2][u], ov = g2[3][u];
            float cn = fv * c2s[u] + iv * gv;
            c2s[u] = cn;
            const int wr = use_hist ? p : (p & 1);
            st_pair(h2t + (size_t)wr * 1024 + (wg << 2) + u,
                    ov * tanh_f(cn), (u32)(p + 1));
        }

        // ---- fallback out-path (no hist workspace): WG0, out(p-2) ----
        if (!use_hist && wg == 0 && p >= 2) {
            const float2 wo0 = *(const float2*)(Wout + (tid << 1));
            const float2 wo1 = *(const float2*)(Wout + HID + (tid << 1));
            float q0 = wo0.x * sb0 + wo0.y * sb1;
            float q1 = wo1.x * sb0 + wo1.y * sb1;
            #pragma unroll
            for (int m = 1; m < 64; m <<= 1) {
                q0 += __shfl_xor(q0, m);
                q1 += __shfl_xor(q1, m);
            }
            if (lane == 0) { red0[wave] = q0; red1[wave] = q1; }
            __syncthreads();
            if (tid == 0) {
                float o0 = bout[0], o1 = bout[1];
                #pragma unroll
                for (int w = 0; w < 8; ++w) { o0 += red0[w]; o1 += red1[w]; }
                out[2*(p-2)+0] = o0;
                out[2*(p-2)+1] = o1;
            }
            __syncthreads();
        }
        // no grid barrier: next phase's poll is the synchronization
    }

    // ---- epilogue ----
    if (use_hist) {
        const float2 wo0 = *(const float2*)(Wout + (tid << 1));
        const float2 wo1 = *(const float2*)(Wout + HID + (tid << 1));
        const float bo0 = bout[0], bo1 = bout[1];
        for (int i = 0; i < 16; ++i) {
            const int t = (wg << 4) + i;
            const u64* hp = h2t + (size_t)(t + 1) * 1024 + (tid << 1);
            const u32 want = (u32)(t + 2);
            u64 va, vb; int guard = 0;
            for (;;) {
                va = ld_pair(hp); vb = ld_pair(hp + 1);
                if ((PTAG(va) == want) && (PTAG(vb) == want)) break;
                if (++guard > (1 << 15)) break;
            }
            float h0 = PVAL(va), h1v = PVAL(vb);
            float q0 = wo0.x * h0 + wo0.y * h1v;
            float q1 = wo1.x * h0 + wo1.y * h1v;
            #pragma unroll
            for (int m = 1; m < 64; m <<= 1) {
                q0 += __shfl_xor(q0, m);
                q1 += __shfl_xor(q1, m);
            }
            if (lane == 0) { red0[wave] = q0; red1[wave] = q1; }
            __syncthreads();
            if (tid == 0) {
                float o0 = bo0, o1 = bo1;
                #pragma unroll
                for (int w = 0; w < 8; ++w) { o0 += red0[w]; o1 += red1[w]; }
                out[2*t+0] = o0;
                out[2*t+1] = o1;
            }
            __syncthreads();
        }
    } else if (wg == 0) {
        // final out[T-1]: h2(T-1) written phase TSTEPS -> row TSTEPS&1 = 0,
        // tag TSTEPS+1
        const float2 wo0 = *(const float2*)(Wout + (tid << 1));
        const float2 wo1 = *(const float2*)(Wout + HID + (tid << 1));
        const u64* hp = h2t + (size_t)(TSTEPS & 1) * 1024 + (tid << 1);
        const u32 want = (u32)(TSTEPS + 1);
        u64 va, vb; int guard = 0;
        for (;;) {
            va = ld_pair(hp); vb = ld_pair(hp + 1);
            if ((PTAG(va) == want) && (PTAG(vb) == want)) break;
            if (++guard > (1 << 15)) break;
        }
        float h0 = PVAL(va), h1v = PVAL(vb);
        float q0 = wo0.x * h0 + wo0.y * h1v;
        float q1 = wo1.x * h0 + wo1.y * h1v;
        #pragma unroll
        for (int m = 1; m < 64; m <<= 1) {
            q0 += __shfl_xor(q0, m);
            q1 += __shfl_xor(q1, m);
        }
        if (lane == 0) { red0[wave] = q0; red1[wave] = q1; }
        __syncthreads();
        if (tid == 0) {
            float o0 = bout[0], o1 = bout[1];
            #pragma unroll
            for (int w = 0; w < 8; ++w) { o0 += red0[w]; o1 += red1[w]; }
            out[2*(TSTEPS-1)+0] = o0;
            out[2*(TSTEPS-1)+1] = o1;
        }
    }
}

extern "C" void kernel_launch(void* const* d_in, const int* in_sizes, int n_in,
                              void* d_out, int out_size, void* d_ws, size_t ws_size,
                              hipStream_t stream)
{
    const float* x    = (const float*)d_in[0];
    const float* Wih1 = (const float*)d_in[1];
    const float* Whh1 = (const float*)d_in[2];
    const float* bih1 = (const float*)d_in[3];
    const float* bhh1 = (const float*)d_in[4];
    const float* Wih2 = (const float*)d_in[5];
    const float* Whh2 = (const float*)d_in[6];
    const float* bih2 = (const float*)d_in[7];
    const float* bhh2 = (const float*)d_in[8];
    const float* Wout = (const float*)d_in[9];
    const float* bout = (const float*)d_in[10];
    float* out = (float*)d_out;
    u64*   ws  = (u64*)d_ws;

    const int use_hist = (ws_size >= WS_NEED_BYTES) ? 1 : 0;

    // allow >64KB dynamic LDS (idempotent, not stream-ordered: capture-safe)
    (void)hipFuncSetAttribute((const void*)lstm_persistent,
                              hipFuncAttributeMaxDynamicSharedMemorySize,
                              DYN_LDS_BYTES);

    // zero h1 slots + h2 rows 0..1 (ws re-poisoned 0xAA before every call;
    // poison can never equal a wanted tag, so un-zeroed hist rows are safe)
    (void)hipMemsetAsync(d_ws, 0, WS_ZERO_BYTES, stream);

    hipLaunchKernelGGL(lstm_persistent, dim3(NWG), dim3(TPB), DYN_LDS_BYTES,
                       stream,
                       x, Wih1, Whh1, bih1, bhh1,
                       Wih2, Whh2, bih2, bhh2,
                       Wout, bout, out, ws, use_hist);
}